// Round 1
// baseline (114.212 us; speedup 1.0000x reference)
//
#include <hip/hip_runtime.h>
#include <hip/hip_bf16.h>

// Problem: B=128, M=256, T=512, N=512
// attn[b,0,n] = softmax_n( sum_k tanh(g[b,k] + sum_t X[b,t,n]*We2[t,k]) * v[k] )
// with g[b,k] = (concat(hidden,cell)[b] @ We1)[k] + be1[k] + be2[k]   (bv cancels in softmax)

typedef _Float16 half8 __attribute__((ext_vector_type(8)));
typedef float floatx4 __attribute__((ext_vector_type(4)));

__device__ __forceinline__ float fast_tanh(float x) {
    float cx = fminf(15.0f, fmaxf(-15.0f, x));
    float e = __expf(2.0f * cx);                 // e^(2x)
    return (e - 1.0f) * __fdividef(1.0f, e + 1.0f);
}

// ---------------- K0: A16[k][t] = (f16) We2[t][k]  (transpose+convert) ----------------
__global__ __launch_bounds__(256) void k_transpose_w2(const float* __restrict__ We2,
                                                      _Float16* __restrict__ A16) {
    __shared__ float tile[64 * 65];
    const int t0 = (blockIdx.x & 7) << 6;
    const int k0 = (blockIdx.x >> 3) << 6;
    const int c  = threadIdx.x & 63;
    const int rb = threadIdx.x >> 6;
#pragma unroll
    for (int i = 0; i < 16; ++i) {
        int r = (i << 2) + rb;
        tile[r * 65 + c] = We2[(t0 + r) * 512 + k0 + c];      // coalesced read
    }
    __syncthreads();
#pragma unroll
    for (int i = 0; i < 16; ++i) {
        int r = (i << 2) + rb;                                 // local k row
        A16[(size_t)(k0 + r) * 512 + t0 + c] = (_Float16)tile[c * 65 + r];  // coalesced write
    }
}

// ---------------- K1: g[b][k] = hc@We1 + be1 + be2 ----------------
__global__ __launch_bounds__(256) void k_hs(const float* __restrict__ hidden,
                                            const float* __restrict__ cell,
                                            const float* __restrict__ We1,
                                            const float* __restrict__ be1,
                                            const float* __restrict__ be2,
                                            float* __restrict__ g) {
    __shared__ __align__(16) float hcl[8][512];
    __shared__ float red[4][8][64];
    const int b0 = (blockIdx.x >> 3) << 3;   // 16 b-blocks of 8
    const int k0 = (blockIdx.x & 7) << 6;    // 8 k-blocks of 64
    for (int idx = threadIdx.x; idx < 8 * 512; idx += 256) {
        int bi = idx >> 9, j = idx & 511;
        hcl[bi][j] = (j < 256) ? hidden[(b0 + bi) * 256 + j]
                               : cell[(b0 + bi) * 256 + j - 256];
    }
    __syncthreads();
    const int kl = threadIdx.x & 63;
    const int jc = threadIdx.x >> 6;
    const int k  = k0 + kl;
    float acc[8] = {};
    for (int j = jc * 128; j < jc * 128 + 128; j += 4) {
        float w0 = We1[(j + 0) * 512 + k];
        float w1 = We1[(j + 1) * 512 + k];
        float w2 = We1[(j + 2) * 512 + k];
        float w3 = We1[(j + 3) * 512 + k];
#pragma unroll
        for (int bi = 0; bi < 8; ++bi) {
            float4 h = *(const float4*)&hcl[bi][j];
            acc[bi] += h.x * w0 + h.y * w1 + h.z * w2 + h.w * w3;
        }
    }
#pragma unroll
    for (int bi = 0; bi < 8; ++bi) red[jc][bi][kl] = acc[bi];
    __syncthreads();
    for (int idx = threadIdx.x; idx < 512; idx += 256) {
        int bi = idx >> 6, kk = idx & 63;
        float s = red[0][bi][kk] + red[1][bi][kk] + red[2][bi][kk] + red[3][bi][kk];
        int kg = k0 + kk;
        g[(b0 + bi) * 512 + kg] = s + be1[kg] + be2[kg];
    }
}

// ---------------- K2: main fused GEMM + tanh + v-dot -> e[b][n] ----------------
// grid = 128 b * 8 nblocks(64).  256 threads = 4 waves; wave w owns k rows [w*128, w*128+128).
// LDS: X^T tile [64 n][512 t] f16, XOR-swizzled (t ^= (n&7)<<3) -> exactly 64 KiB.
__global__ __launch_bounds__(256, 2) void k_main(const float* __restrict__ X,
                                                 const _Float16* __restrict__ A16,
                                                 const float* __restrict__ g,
                                                 const float* __restrict__ vvec,
                                                 float* __restrict__ E) {
    __shared__ __align__(16) _Float16 XT[64 * 512];
    const int b    = blockIdx.x >> 3;
    const int n0   = (blockIdx.x & 7) << 6;
    const int tid  = threadIdx.x;
    const int lane = tid & 63;
    const int wv   = tid >> 6;

    // ---- stage X^T tile: f32 coalesced load (lane = n), pack 8 t's, swizzled b128 write
    {
        const float* Xb = X + (size_t)b * (512 * 512);
        const int nl = tid & 63;
        const int tg = (tid >> 6) << 3;  // 0,8,16,24
#pragma unroll 2
        for (int pass = 0; pass < 16; ++pass) {
            int t0 = pass * 32 + tg;
            float f[8];
#pragma unroll
            for (int i = 0; i < 8; ++i) f[i] = Xb[(size_t)(t0 + i) * 512 + n0 + nl];
            half8 h;
#pragma unroll
            for (int i = 0; i < 8; ++i) h[i] = (_Float16)f[i];
            *(half8*)&XT[nl * 512 + (t0 ^ ((nl & 7) << 3))] = h;
        }
    }
    __syncthreads();

    const int l16 = lane & 15;
    const int lhi = lane >> 4;
    floatx4 acc[8][4];
#pragma unroll
    for (int a = 0; a < 8; ++a)
#pragma unroll
        for (int c = 0; c < 4; ++c) acc[a][c] = (floatx4){0.f, 0.f, 0.f, 0.f};

    const _Float16* Aw = A16 + (size_t)(wv * 128) * 512;
    // barrier-free main loop: K=512 in 16 steps of 32
    for (int ts = 0; ts < 16; ++ts) {
        const int t0 = ts * 32 + lhi * 8;
        half8 af[8], bf[4];
#pragma unroll
        for (int kf = 0; kf < 8; ++kf)
            af[kf] = *(const half8*)&Aw[(size_t)(kf * 16 + l16) * 512 + t0];
#pragma unroll
        for (int nf = 0; nf < 4; ++nf) {
            int n = nf * 16 + l16;
            bf[nf] = *(const half8*)&XT[n * 512 + (t0 ^ ((n & 7) << 3))];
        }
#pragma unroll
        for (int kf = 0; kf < 8; ++kf)
#pragma unroll
            for (int nf = 0; nf < 4; ++nf)
                acc[kf][nf] = __builtin_amdgcn_mfma_f32_16x16x32_f16(af[kf], bf[nf], acc[kf][nf], 0, 0, 0);
    }

    // ---- fused epilogue: s[n] = sum_k tanh(acc + g[k]) * v[k]
    // C/D layout (16x16x32): col n = lane&15, row k = (lane>>4)*4 + reg
    const float* gb = g + b * 512;
    float s[4] = {0.f, 0.f, 0.f, 0.f};
#pragma unroll
    for (int kf = 0; kf < 8; ++kf) {
        const int kb = wv * 128 + kf * 16 + lhi * 4;
        float g0 = gb[kb + 0], g1 = gb[kb + 1], g2 = gb[kb + 2], g3 = gb[kb + 3];
        float v0 = vvec[kb + 0], v1 = vvec[kb + 1], v2 = vvec[kb + 2], v3 = vvec[kb + 3];
#pragma unroll
        for (int nf = 0; nf < 4; ++nf) {
            s[nf] += fast_tanh(acc[kf][nf][0] + g0) * v0;
            s[nf] += fast_tanh(acc[kf][nf][1] + g1) * v1;
            s[nf] += fast_tanh(acc[kf][nf][2] + g2) * v2;
            s[nf] += fast_tanh(acc[kf][nf][3] + g3) * v3;
        }
    }
    // reduce over the 4 lane-groups (rows within the wave's k-frags)
#pragma unroll
    for (int nf = 0; nf < 4; ++nf) {
        s[nf] += __shfl_xor(s[nf], 16);
        s[nf] += __shfl_xor(s[nf], 32);
    }
    __syncthreads();               // all XT reads done -> reuse LDS
    float* ered = (float*)XT;      // [4 waves][64 n]
    if (lane < 16) {
#pragma unroll
        for (int nf = 0; nf < 4; ++nf) ered[wv * 64 + nf * 16 + lane] = s[nf];
    }
    __syncthreads();
    if (tid < 64) {
        float e = ered[tid] + ered[64 + tid] + ered[128 + tid] + ered[192 + tid];
        E[b * 512 + n0 + tid] = e;
    }
}

// ---------------- K3: softmax over n (512) per batch row ----------------
__global__ __launch_bounds__(256) void k_softmax(const float* __restrict__ E,
                                                 float* __restrict__ out) {
    __shared__ float rmax[4], rsum[4];
    const int b = blockIdx.x;
    const int tid = threadIdx.x;
    float e0 = E[b * 512 + tid];
    float e1 = E[b * 512 + 256 + tid];
    float m = fmaxf(e0, e1);
    for (int o = 32; o > 0; o >>= 1) m = fmaxf(m, __shfl_xor(m, o));
    if ((tid & 63) == 0) rmax[tid >> 6] = m;
    __syncthreads();
    m = fmaxf(fmaxf(rmax[0], rmax[1]), fmaxf(rmax[2], rmax[3]));
    float p0 = __expf(e0 - m), p1 = __expf(e1 - m);
    float ss = p0 + p1;
    for (int o = 32; o > 0; o >>= 1) ss += __shfl_xor(ss, o);
    if ((tid & 63) == 0) rsum[tid >> 6] = ss;
    __syncthreads();
    ss = rsum[0] + rsum[1] + rsum[2] + rsum[3];
    float inv = __fdividef(1.0f, ss);
    out[b * 512 + tid] = p0 * inv;
    out[b * 512 + 256 + tid] = p1 * inv;
}

extern "C" void kernel_launch(void* const* d_in, const int* in_sizes, int n_in,
                              void* d_out, int out_size, void* d_ws, size_t ws_size,
                              hipStream_t stream) {
    const float* hidden = (const float*)d_in[0];
    const float* cell   = (const float*)d_in[1];
    const float* X      = (const float*)d_in[2];
    const float* We1    = (const float*)d_in[3];
    const float* be1    = (const float*)d_in[4];
    const float* We2    = (const float*)d_in[5];
    const float* be2    = (const float*)d_in[6];
    const float* v      = (const float*)d_in[7];
    float* out = (float*)d_out;

    char* ws = (char*)d_ws;
    _Float16* A16 = (_Float16*)ws;                       // 512*512*2  = 524288 B
    float* g      = (float*)(ws + 524288);               // 128*512*4  = 262144 B
    float* E      = (float*)(ws + 524288 + 262144);      // 128*512*4  = 262144 B

    k_transpose_w2<<<64, 256, 0, stream>>>(We2, A16);
    k_hs<<<128, 256, 0, stream>>>(hidden, cell, We1, be1, be2, g);
    k_main<<<1024, 256, 0, stream>>>(X, A16, g, v, E);
    k_softmax<<<128, 256, 0, stream>>>(E, out);
}

// Round 2
// 88.255 us; speedup vs baseline: 1.2941x; 1.2941x over previous
//
#include <hip/hip_runtime.h>
#include <hip/hip_bf16.h>

// Problem: B=128, M=256, T=512, N=512
// attn[b,0,n] = softmax_n( sum_k tanh(g[b,k] + sum_t X[b,t,n]*We2[t,k]) * v[k] )
// with g[b,k] = (concat(hidden,cell)[b] @ We1)[k] + be1[k] + be2[k]   (bv cancels in softmax)

typedef _Float16 half8 __attribute__((ext_vector_type(8)));
typedef float floatx4 __attribute__((ext_vector_type(4)));

__device__ __forceinline__ float fast_tanh(float x) {
    float cx = fminf(15.0f, fmaxf(-15.0f, x));
    float e = __expf(2.0f * cx);                 // e^(2x)
    return (e - 1.0f) * __fdividef(1.0f, e + 1.0f);
}

// ---------------- K0: Af = We2^T in MFMA-fragment order ----------------
// Af chunk index ((kb*16 + ts)*64 + lane)*8 holds A[k = kb*16 + (lane&15)]
// [t = ts*32 + (lane>>4)*8 + j], j=0..7.  One wave A-frag load = 1KB contiguous.
__global__ __launch_bounds__(256) void k_prep_a(const float* __restrict__ We2,
                                                _Float16* __restrict__ Af) {
    __shared__ float tile[64][65];
    const int t0 = (blockIdx.x & 7) << 6;
    const int k0 = (blockIdx.x >> 3) << 6;
    const int c  = threadIdx.x & 63;
    const int rb = threadIdx.x >> 6;
#pragma unroll
    for (int i = 0; i < 16; ++i) {
        int r = (i << 2) + rb;
        tile[r][c] = We2[(t0 + r) * 512 + k0 + c];        // coalesced read
    }
    __syncthreads();
#pragma unroll
    for (int i = 0; i < 2; ++i) {
        int id   = threadIdx.x + (i << 8);                // 0..511
        int kbl  = id >> 7;                               // 0..3
        int tsl  = (id >> 6) & 1;                         // 0..1
        int lane = id & 63;
        int kloc = kbl * 16 + (lane & 15);
        int tloc = tsl * 32 + (lane >> 4) * 8;
        half8 h;
#pragma unroll
        for (int j = 0; j < 8; ++j) h[j] = (_Float16)tile[tloc + j][kloc];
        int kb = (k0 >> 4) + kbl;
        int ts = (t0 >> 5) + tsl;
        *(half8*)&Af[(((size_t)kb * 16 + ts) * 64 + lane) * 8] = h;  // coalesced write
    }
}

// ---------------- K1: g[b][k] = hc@We1 + be1 + be2 ----------------
__global__ __launch_bounds__(256) void k_hs(const float* __restrict__ hidden,
                                            const float* __restrict__ cell,
                                            const float* __restrict__ We1,
                                            const float* __restrict__ be1,
                                            const float* __restrict__ be2,
                                            float* __restrict__ g) {
    __shared__ __align__(16) float hcl[8][512];
    __shared__ float red[4][8][64];
    const int b0 = (blockIdx.x >> 3) << 3;   // 16 b-blocks of 8
    const int k0 = (blockIdx.x & 7) << 6;    // 8 k-blocks of 64
    for (int idx = threadIdx.x; idx < 8 * 512; idx += 256) {
        int bi = idx >> 9, j = idx & 511;
        hcl[bi][j] = (j < 256) ? hidden[(b0 + bi) * 256 + j]
                               : cell[(b0 + bi) * 256 + j - 256];
    }
    __syncthreads();
    const int kl = threadIdx.x & 63;
    const int jc = threadIdx.x >> 6;
    const int k  = k0 + kl;
    float acc[8] = {};
    for (int j = jc * 128; j < jc * 128 + 128; j += 4) {
        float w0 = We1[(j + 0) * 512 + k];
        float w1 = We1[(j + 1) * 512 + k];
        float w2 = We1[(j + 2) * 512 + k];
        float w3 = We1[(j + 3) * 512 + k];
#pragma unroll
        for (int bi = 0; bi < 8; ++bi) {
            float4 h = *(const float4*)&hcl[bi][j];
            acc[bi] += h.x * w0 + h.y * w1 + h.z * w2 + h.w * w3;
        }
    }
#pragma unroll
    for (int bi = 0; bi < 8; ++bi) red[jc][bi][kl] = acc[bi];
    __syncthreads();
    for (int idx = threadIdx.x; idx < 512; idx += 256) {
        int bi = idx >> 6, kk = idx & 63;
        float s = red[0][bi][kk] + red[1][bi][kk] + red[2][bi][kk] + red[3][bi][kk];
        int kg = k0 + kk;
        g[(b0 + bi) * 512 + kg] = s + be1[kg] + be2[kg];
    }
}

// ---------------- K2: fused GEMM + tanh + v-dot -> e[b][n] ----------------
// grid = 128 b * 16 nblocks(32).  512 threads = 8 waves; wave w owns k rows
// [w*64, w*64+64).  LDS: X^T tile [32 n][512 t] f16, swizzled, = 32 KiB ->
// 2 blocks/CU, 16 waves/CU.  A-frags stream coalesced from Af with 1-deep
// register double-buffer.
__global__ __launch_bounds__(512, 4) void k_main(const float* __restrict__ X,
                                                 const _Float16* __restrict__ Af,
                                                 const float* __restrict__ g,
                                                 const float* __restrict__ vvec,
                                                 float* __restrict__ E) {
    __shared__ __align__(16) _Float16 XT[32 * 512];
    const int b    = blockIdx.x >> 4;
    const int n0   = (blockIdx.x & 15) << 5;
    const int tid  = threadIdx.x;
    const int lane = tid & 63;
    const int wv   = tid >> 6;

    // ---- stage X^T tile: coalesced f32 loads, f16 pack, swizzled b128 writes
    {
        const float* Xb = X + (size_t)b * (512 * 512);
        const int nl = tid & 31;
        const int tg = tid >> 5;             // 0..15
#pragma unroll
        for (int p = 0; p < 4; ++p) {
            int t0 = p * 128 + tg * 8;
            float f[8];
#pragma unroll
            for (int i = 0; i < 8; ++i) f[i] = Xb[(size_t)(t0 + i) * 512 + n0 + nl];
            half8 h;
#pragma unroll
            for (int i = 0; i < 8; ++i) h[i] = (_Float16)f[i];
            *(half8*)&XT[nl * 512 + (t0 ^ ((nl & 7) << 3))] = h;
        }
    }
    __syncthreads();

    const int l16 = lane & 15;
    const int lhi = lane >> 4;
    floatx4 acc[4][2];
#pragma unroll
    for (int a = 0; a < 4; ++a)
#pragma unroll
        for (int c = 0; c < 2; ++c) acc[a][c] = (floatx4){0.f, 0.f, 0.f, 0.f};

    // per-thread A base: Af + wv*64*512 + lane*8 ; + kf*8192 + ts*512
    const _Float16* __restrict__ Ap = Af + (size_t)wv * 32768 + (size_t)lane * 8;

    half8 afA[4], afB[4], bfA[2], bfB[2];
    // prime ts = 0
#pragma unroll
    for (int kf = 0; kf < 4; ++kf) afA[kf] = *(const half8*)&Ap[(size_t)kf * 8192];
#pragma unroll
    for (int nf = 0; nf < 2; ++nf) {
        int n = nf * 16 + l16;
        bfA[nf] = *(const half8*)&XT[n * 512 + ((lhi * 8) ^ ((n & 7) << 3))];
    }

    for (int ts = 0; ts < 16; ts += 2) {
        // prefetch ts+1 -> B set (ts+1 <= 15 always)
#pragma unroll
        for (int kf = 0; kf < 4; ++kf)
            afB[kf] = *(const half8*)&Ap[(size_t)kf * 8192 + (ts + 1) * 512];
#pragma unroll
        for (int nf = 0; nf < 2; ++nf) {
            int n  = nf * 16 + l16;
            int t0 = (ts + 1) * 32 + lhi * 8;
            bfB[nf] = *(const half8*)&XT[n * 512 + (t0 ^ ((n & 7) << 3))];
        }
#pragma unroll
        for (int kf = 0; kf < 4; ++kf)
#pragma unroll
            for (int nf = 0; nf < 2; ++nf)
                acc[kf][nf] = __builtin_amdgcn_mfma_f32_16x16x32_f16(afA[kf], bfA[nf], acc[kf][nf], 0, 0, 0);
        if (ts + 2 < 16) {
            // prefetch ts+2 -> A set
#pragma unroll
            for (int kf = 0; kf < 4; ++kf)
                afA[kf] = *(const half8*)&Ap[(size_t)kf * 8192 + (ts + 2) * 512];
#pragma unroll
            for (int nf = 0; nf < 2; ++nf) {
                int n  = nf * 16 + l16;
                int t0 = (ts + 2) * 32 + lhi * 8;
                bfA[nf] = *(const half8*)&XT[n * 512 + (t0 ^ ((n & 7) << 3))];
            }
        }
#pragma unroll
        for (int kf = 0; kf < 4; ++kf)
#pragma unroll
            for (int nf = 0; nf < 2; ++nf)
                acc[kf][nf] = __builtin_amdgcn_mfma_f32_16x16x32_f16(afB[kf], bfB[nf], acc[kf][nf], 0, 0, 0);
    }

    // ---- fused epilogue: s[n] = sum_k tanh(acc + g[k]) * v[k]
    // C/D layout (16x16x32): col n = lane&15, row k = (lane>>4)*4 + reg
    const float* gb = g + b * 512;
    float s0 = 0.f, s1 = 0.f;
#pragma unroll
    for (int kf = 0; kf < 4; ++kf) {
        const int kb = wv * 64 + kf * 16 + lhi * 4;
        float g0 = gb[kb + 0], g1 = gb[kb + 1], g2 = gb[kb + 2], g3 = gb[kb + 3];
        float v0 = vvec[kb + 0], v1 = vvec[kb + 1], v2 = vvec[kb + 2], v3 = vvec[kb + 3];
        s0 += fast_tanh(acc[kf][0][0] + g0) * v0;
        s0 += fast_tanh(acc[kf][0][1] + g1) * v1;
        s0 += fast_tanh(acc[kf][0][2] + g2) * v2;
        s0 += fast_tanh(acc[kf][0][3] + g3) * v3;
        s1 += fast_tanh(acc[kf][1][0] + g0) * v0;
        s1 += fast_tanh(acc[kf][1][1] + g1) * v1;
        s1 += fast_tanh(acc[kf][1][2] + g2) * v2;
        s1 += fast_tanh(acc[kf][1][3] + g3) * v3;
    }
    s0 += __shfl_xor(s0, 16);  s0 += __shfl_xor(s0, 32);
    s1 += __shfl_xor(s1, 16);  s1 += __shfl_xor(s1, 32);

    __syncthreads();               // all XT reads done -> reuse LDS
    float* ered = (float*)XT;      // [8 waves][32 n]
    if (lane < 16) {
        ered[wv * 32 + l16]      = s0;
        ered[wv * 32 + 16 + l16] = s1;
    }
    __syncthreads();
    if (tid < 32) {
        float e = 0.f;
#pragma unroll
        for (int w = 0; w < 8; ++w) e += ered[w * 32 + tid];
        E[b * 512 + n0 + tid] = e;
    }
}

// ---------------- K3: softmax over n (512) per batch row ----------------
__global__ __launch_bounds__(256) void k_softmax(const float* __restrict__ E,
                                                 float* __restrict__ out) {
    __shared__ float rmax[4], rsum[4];
    const int b = blockIdx.x;
    const int tid = threadIdx.x;
    float e0 = E[b * 512 + tid];
    float e1 = E[b * 512 + 256 + tid];
    float m = fmaxf(e0, e1);
    for (int o = 32; o > 0; o >>= 1) m = fmaxf(m, __shfl_xor(m, o));
    if ((tid & 63) == 0) rmax[tid >> 6] = m;
    __syncthreads();
    m = fmaxf(fmaxf(rmax[0], rmax[1]), fmaxf(rmax[2], rmax[3]));
    float p0 = __expf(e0 - m), p1 = __expf(e1 - m);
    float ss = p0 + p1;
    for (int o = 32; o > 0; o >>= 1) ss += __shfl_xor(ss, o);
    if ((tid & 63) == 0) rsum[tid >> 6] = ss;
    __syncthreads();
    ss = rsum[0] + rsum[1] + rsum[2] + rsum[3];
    float inv = __fdividef(1.0f, ss);
    out[b * 512 + tid] = p0 * inv;
    out[b * 512 + 256 + tid] = p1 * inv;
}

extern "C" void kernel_launch(void* const* d_in, const int* in_sizes, int n_in,
                              void* d_out, int out_size, void* d_ws, size_t ws_size,
                              hipStream_t stream) {
    const float* hidden = (const float*)d_in[0];
    const float* cell   = (const float*)d_in[1];
    const float* X      = (const float*)d_in[2];
    const float* We1    = (const float*)d_in[3];
    const float* be1    = (const float*)d_in[4];
    const float* We2    = (const float*)d_in[5];
    const float* be2    = (const float*)d_in[6];
    const float* v      = (const float*)d_in[7];
    float* out = (float*)d_out;

    char* ws = (char*)d_ws;
    _Float16* Af = (_Float16*)ws;                        // 512*512*2  = 524288 B
    float* g     = (float*)(ws + 524288);                // 128*512*4  = 262144 B
    float* E     = (float*)(ws + 524288 + 262144);       // 128*512*4  = 262144 B

    k_prep_a<<<64, 256, 0, stream>>>(We2, Af);
    k_hs<<<128, 256, 0, stream>>>(hidden, cell, We1, be1, be2, g);
    k_main<<<2048, 512, 0, stream>>>(X, Af, g, v, E);
    k_softmax<<<128, 256, 0, stream>>>(E, out);
}

// Round 3
// 83.333 us; speedup vs baseline: 1.3706x; 1.0591x over previous
//
#include <hip/hip_runtime.h>
#include <hip/hip_bf16.h>

// Problem: B=128, M=256, T=512, N=512
// attn[b,0,n] = softmax_n( sum_k tanh(g[b,k] + sum_t X[b,t,n]*We2[t,k]) * v[k] )
// g[b,k] = (concat(hidden,cell)[b] @ We1)[k] + be1[k] + be2[k]   (bv cancels in softmax)

typedef _Float16 half8 __attribute__((ext_vector_type(8)));
typedef _Float16 half4 __attribute__((ext_vector_type(4)));
typedef float floatx4 __attribute__((ext_vector_type(4)));

__device__ __forceinline__ float fast_tanh(float x) {
    float cx = fminf(15.0f, fmaxf(-15.0f, x));
    float e = __expf(2.0f * cx);
    return (e - 1.0f) * __fdividef(1.0f, e + 1.0f);
}

// ---------------- K0: Af in per-ts frag-linear order ----------------
// 16B-unit u = ((ts*8+wv)*4 + kf)*64 + lane holds A[k=wv*64+kf*16+(lane&15)]
// [t = ts*32 + (lane>>4)*8 + j], j=0..7.   (A = We2^T, f16)
__global__ __launch_bounds__(256) void k_prep_a(const float* __restrict__ We2,
                                                _Float16* __restrict__ Af) {
    __shared__ float w2[32][512];
    const int ts = blockIdx.x;            // 16 blocks, t-range 32 each
    for (int idx = threadIdx.x; idx < 32 * 512; idx += 256) {
        int tl = idx >> 9, k = idx & 511;
        w2[tl][k] = We2[(ts * 32 + tl) * 512 + k];     // coalesced
    }
    __syncthreads();
    for (int item = threadIdx.x; item < 32 * 64; item += 256) {
        int c = item >> 6, l = item & 63;              // c = wv*4+kf
        int k  = (c >> 2) * 64 + (c & 3) * 16 + (l & 15);
        int tl = (l >> 4) * 8;
        half8 h;
#pragma unroll
        for (int j = 0; j < 8; ++j) h[j] = (_Float16)w2[tl + j][k];
        *(half8*)&Af[(((size_t)ts * 32 + c) * 64 + l) * 8] = h;   // coalesced
    }
}

// ---------------- K1: g[b][k] = hc@We1 + be1 + be2 ----------------
__global__ __launch_bounds__(256) void k_hs(const float* __restrict__ hidden,
                                            const float* __restrict__ cell,
                                            const float* __restrict__ We1,
                                            const float* __restrict__ be1,
                                            const float* __restrict__ be2,
                                            float* __restrict__ g) {
    __shared__ __align__(16) float hcl[8][512];
    __shared__ float red[4][8][64];
    const int b0 = (blockIdx.x >> 3) << 3;
    const int k0 = (blockIdx.x & 7) << 6;
    for (int idx = threadIdx.x; idx < 8 * 512; idx += 256) {
        int bi = idx >> 9, j = idx & 511;
        hcl[bi][j] = (j < 256) ? hidden[(b0 + bi) * 256 + j]
                               : cell[(b0 + bi) * 256 + j - 256];
    }
    __syncthreads();
    const int kl = threadIdx.x & 63;
    const int jc = threadIdx.x >> 6;
    const int k  = k0 + kl;
    float acc[8] = {};
    for (int j = jc * 128; j < jc * 128 + 128; j += 4) {
        float w0 = We1[(j + 0) * 512 + k];
        float w1 = We1[(j + 1) * 512 + k];
        float w2 = We1[(j + 2) * 512 + k];
        float w3 = We1[(j + 3) * 512 + k];
#pragma unroll
        for (int bi = 0; bi < 8; ++bi) {
            float4 h = *(const float4*)&hcl[bi][j];
            acc[bi] += h.x * w0 + h.y * w1 + h.z * w2 + h.w * w3;
        }
    }
#pragma unroll
    for (int bi = 0; bi < 8; ++bi) red[jc][bi][kl] = acc[bi];
    __syncthreads();
    for (int idx = threadIdx.x; idx < 512; idx += 256) {
        int bi = idx >> 6, kk = idx & 63;
        float s = red[0][bi][kk] + red[1][bi][kk] + red[2][bi][kk] + red[3][bi][kk];
        int kg = k0 + kk;
        g[(b0 + bi) * 512 + kg] = s + be1[kg] + be2[kg];
    }
}

// ---------------- K2: fused GEMM + tanh + v-dot -> e[b][n] ----------------
// grid = 128 b * 8 nblocks(64).  512 threads = 8 waves; wave wv owns k
// [wv*64, wv*64+64) (4 kf) x n 64 (4 nf) -> 16 MFMA / t-step.
// LDS: A dbuf 2x32KB frag-linear; X dbuf 2x4.5KB transposed f16 (pair+XOR
// layout).  73 KB total -> 2 blocks/CU; resident-block overlap hides staging.
__global__ __launch_bounds__(512, 4) void k_main(const float* __restrict__ X,
                                                 const _Float16* __restrict__ Af,
                                                 const float* __restrict__ g,
                                                 const float* __restrict__ vvec,
                                                 float* __restrict__ E) {
    __shared__ __align__(16) _Float16 Abuf[2][16384];   // 2 x 32 KiB
    __shared__ __align__(16) _Float16 Xbuf[2][2304];    // 2 x 4.5 KiB
    const int b    = blockIdx.x >> 3;
    const int n0   = (blockIdx.x & 7) << 6;
    const int tid  = threadIdx.x;
    const int lane = tid & 63;
    const int wv   = tid >> 6;
    const int l16  = lane & 15;
    const int lhi  = lane >> 4;

    const float* Xb = X + (size_t)b * (512 * 512);

    // X-stage thread map: xw = wave (t-group of 4), xc = lane (n).
    // Xbuf layout (halves): off(n,t) = (n>>1)*72 + (n&1)*32 + (t ^ ((n&3)<<3))
    const int xw  = wv;
    const int xc  = lane;
    const int xwr = (xc >> 1) * 72 + (xc & 1) * 32 + ((4 * xw) ^ ((xc & 3) << 3));

    float xr0, xr1, xr2, xr3;          // X-stage regs
    half8 as0, as1, as2, as3;          // A-stage regs

    // ---- prologue: stage ts = 0 ----
    {
        const _Float16* ap = Af + (size_t)tid * 8;     // ts=0 chunk
        as0 = *(const half8*)(ap);
        as1 = *(const half8*)(ap + 4096);
        as2 = *(const half8*)(ap + 8192);
        as3 = *(const half8*)(ap + 12288);
        const float* xp = Xb + (size_t)(4 * xw) * 512 + n0 + xc;
        xr0 = xp[0]; xr1 = xp[512]; xr2 = xp[1024]; xr3 = xp[1536];
        _Float16* lp = &Abuf[0][tid * 8];
        *(half8*)(lp)         = as0;
        *(half8*)(lp + 4096)  = as1;
        *(half8*)(lp + 8192)  = as2;
        *(half8*)(lp + 12288) = as3;
        half4 h;
        h[0] = (_Float16)xr0; h[1] = (_Float16)xr1;
        h[2] = (_Float16)xr2; h[3] = (_Float16)xr3;
        *(half4*)&Xbuf[0][xwr] = h;
    }
    __syncthreads();

    floatx4 acc[4][4];
#pragma unroll
    for (int a = 0; a < 4; ++a)
#pragma unroll
        for (int c = 0; c < 4; ++c) acc[a][c] = (floatx4){0.f, 0.f, 0.f, 0.f};

    for (int ts = 0; ts < 16; ++ts) {
        const int cur = ts & 1;
        // issue next-tile global loads early (T14: write late, after MFMAs)
        if (ts < 15) {
            const _Float16* ap = Af + (size_t)(ts + 1) * 16384 + (size_t)tid * 8;
            as0 = *(const half8*)(ap);
            as1 = *(const half8*)(ap + 4096);
            as2 = *(const half8*)(ap + 8192);
            as3 = *(const half8*)(ap + 12288);
            const float* xp = Xb + (size_t)((ts + 1) * 32 + 4 * xw) * 512 + n0 + xc;
            xr0 = xp[0]; xr1 = xp[512]; xr2 = xp[1024]; xr3 = xp[1536];
        }
        // fragment reads (conflict-free A, ~2-way X) + 16 MFMA
        {
            const _Float16* Ab = &Abuf[cur][wv * 2048 + lane * 8];
            half8 af0 = *(const half8*)(Ab);
            half8 af1 = *(const half8*)(Ab + 512);
            half8 af2 = *(const half8*)(Ab + 1024);
            half8 af3 = *(const half8*)(Ab + 1536);
#pragma unroll
            for (int nf = 0; nf < 4; ++nf) {
                const int n = nf * 16 + l16;
                half8 bf = *(const half8*)&Xbuf[cur][(n >> 1) * 72 + (n & 1) * 32 +
                                                     ((lhi * 8) ^ ((l16 & 3) << 3))];
                acc[0][nf] = __builtin_amdgcn_mfma_f32_16x16x32_f16(af0, bf, acc[0][nf], 0, 0, 0);
                acc[1][nf] = __builtin_amdgcn_mfma_f32_16x16x32_f16(af1, bf, acc[1][nf], 0, 0, 0);
                acc[2][nf] = __builtin_amdgcn_mfma_f32_16x16x32_f16(af2, bf, acc[2][nf], 0, 0, 0);
                acc[3][nf] = __builtin_amdgcn_mfma_f32_16x16x32_f16(af3, bf, acc[3][nf], 0, 0, 0);
            }
        }
        // late writes of the prefetched tile into buf^1
        if (ts < 15) {
            _Float16* lp = &Abuf[cur ^ 1][tid * 8];
            *(half8*)(lp)         = as0;
            *(half8*)(lp + 4096)  = as1;
            *(half8*)(lp + 8192)  = as2;
            *(half8*)(lp + 12288) = as3;
            half4 h;
            h[0] = (_Float16)xr0; h[1] = (_Float16)xr1;
            h[2] = (_Float16)xr2; h[3] = (_Float16)xr3;
            *(half4*)&Xbuf[cur ^ 1][xwr] = h;
        }
        __syncthreads();
    }

    // ---- fused epilogue: s[n] = sum_k tanh(acc + g[k]) * v[k]
    // C/D layout (16x16x32): col n = lane&15, row k = (lane>>4)*4 + reg
    const float* gb = g + b * 512;
    float s[4] = {0.f, 0.f, 0.f, 0.f};
#pragma unroll
    for (int kf = 0; kf < 4; ++kf) {
        const int kb = wv * 64 + kf * 16 + lhi * 4;
        float g0 = gb[kb + 0], g1 = gb[kb + 1], g2 = gb[kb + 2], g3 = gb[kb + 3];
        float v0 = vvec[kb + 0], v1 = vvec[kb + 1], v2 = vvec[kb + 2], v3 = vvec[kb + 3];
#pragma unroll
        for (int nf = 0; nf < 4; ++nf) {
            s[nf] += fast_tanh(acc[kf][nf][0] + g0) * v0;
            s[nf] += fast_tanh(acc[kf][nf][1] + g1) * v1;
            s[nf] += fast_tanh(acc[kf][nf][2] + g2) * v2;
            s[nf] += fast_tanh(acc[kf][nf][3] + g3) * v3;
        }
    }
#pragma unroll
    for (int nf = 0; nf < 4; ++nf) {
        s[nf] += __shfl_xor(s[nf], 16);
        s[nf] += __shfl_xor(s[nf], 32);
    }
    float* ered = (float*)&Abuf[0][0];    // [8 waves][64 n] overlay (reads done)
    if (lane < 16) {
#pragma unroll
        for (int nf = 0; nf < 4; ++nf) ered[wv * 64 + nf * 16 + l16] = s[nf];
    }
    __syncthreads();
    if (tid < 64) {
        float e = 0.f;
#pragma unroll
        for (int w = 0; w < 8; ++w) e += ered[w * 64 + tid];
        E[b * 512 + n0 + tid] = e;
    }
}

// ---------------- K3: softmax over n (512) per batch row ----------------
__global__ __launch_bounds__(256) void k_softmax(const float* __restrict__ E,
                                                 float* __restrict__ out) {
    __shared__ float rmax[4], rsum[4];
    const int b = blockIdx.x;
    const int tid = threadIdx.x;
    float e0 = E[b * 512 + tid];
    float e1 = E[b * 512 + 256 + tid];
    float m = fmaxf(e0, e1);
    for (int o = 32; o > 0; o >>= 1) m = fmaxf(m, __shfl_xor(m, o));
    if ((tid & 63) == 0) rmax[tid >> 6] = m;
    __syncthreads();
    m = fmaxf(fmaxf(rmax[0], rmax[1]), fmaxf(rmax[2], rmax[3]));
    float p0 = __expf(e0 - m), p1 = __expf(e1 - m);
    float ss = p0 + p1;
    for (int o = 32; o > 0; o >>= 1) ss += __shfl_xor(ss, o);
    if ((tid & 63) == 0) rsum[tid >> 6] = ss;
    __syncthreads();
    ss = rsum[0] + rsum[1] + rsum[2] + rsum[3];
    float inv = __fdividef(1.0f, ss);
    out[b * 512 + tid] = p0 * inv;
    out[b * 512 + 256 + tid] = p1 * inv;
}

extern "C" void kernel_launch(void* const* d_in, const int* in_sizes, int n_in,
                              void* d_out, int out_size, void* d_ws, size_t ws_size,
                              hipStream_t stream) {
    const float* hidden = (const float*)d_in[0];
    const float* cell   = (const float*)d_in[1];
    const float* X      = (const float*)d_in[2];
    const float* We1    = (const float*)d_in[3];
    const float* be1    = (const float*)d_in[4];
    const float* We2    = (const float*)d_in[5];
    const float* be2    = (const float*)d_in[6];
    const float* v      = (const float*)d_in[7];
    float* out = (float*)d_out;

    char* ws = (char*)d_ws;
    _Float16* Af = (_Float16*)ws;                        // 512*512*2  = 524288 B
    float* g     = (float*)(ws + 524288);                // 128*512*4  = 262144 B
    float* E     = (float*)(ws + 524288 + 262144);       // 128*512*4  = 262144 B

    k_prep_a<<<16, 256, 0, stream>>>(We2, Af);
    k_hs<<<128, 256, 0, stream>>>(hidden, cell, We1, be1, be2, g);
    k_main<<<1024, 512, 0, stream>>>(X, Af, g, v, E);
    k_softmax<<<128, 256, 0, stream>>>(E, out);
}